// Round 1
// baseline (2090.726 us; speedup 1.0000x reference)
//
#include <hip/hip_runtime.h>

typedef unsigned short u16;
typedef unsigned int u32;
typedef __attribute__((ext_vector_type(8))) short short8;
typedef __attribute__((ext_vector_type(4))) float f32x4;
typedef __attribute__((ext_vector_type(8))) u16 ushort8v;

__device__ __forceinline__ u16 f2bf(float f) {
    union { float f; u32 u; } v; v.f = f;
    u32 u = v.u;
    u32 r = (u + 0x7FFFu + ((u >> 16) & 1u)) >> 16;
    return (u16)r;
}

// ---------------------------------------------------------------------------
// Gather rows of a [*,512] fp32 matrix (1 or 2 level indirection) and write
// the TRANSPOSE as bf16: outT[f][s] = bf16(src[row(s)][f]).  32 s per block.
// ---------------------------------------------------------------------------
__global__ __launch_bounds__(256) void gather_transpose_bf16(
    const float* __restrict__ src, const int* __restrict__ lvl1,
    const int* __restrict__ lvl2, u16* __restrict__ outT, int S)
{
    __shared__ u16 tile[32][514];   // pad 2 -> stride 1028 B (4-aligned, bank-spread)
    const int s0 = blockIdx.x * 32;
    const int tid = threadIdx.x;

    for (int r = 0; r < 32; ++r) {
        int row = lvl1[s0 + r];
        if (lvl2) row = lvl2[row];
        float2 v = *(const float2*)(src + (size_t)row * 512 + tid * 2);
        u32 packed = (u32)f2bf(v.x) | ((u32)f2bf(v.y) << 16);
        *(u32*)&tile[r][tid * 2] = packed;
    }
    __syncthreads();

    #pragma unroll
    for (int i = 0; i < 8; ++i) {
        int f = i * 64 + (tid >> 2);
        int sb = (tid & 3) * 8;
        ushort8v o;
        #pragma unroll
        for (int j = 0; j < 8; ++j) o[j] = tile[sb + j][f];
        *(ushort8v*)(outT + (size_t)f * S + s0 + sb) = o;
    }
}

// ---------------------------------------------------------------------------
// Plain row gather, fp32 -> fp32, F=512. One row per block (128 thr x float4).
// ---------------------------------------------------------------------------
__global__ __launch_bounds__(128) void gather_rows_f32(
    const float* __restrict__ src, const int* __restrict__ lvl1,
    const int* __restrict__ lvl2, float* __restrict__ out)
{
    int b = blockIdx.x;
    int row = lvl1[b];
    if (lvl2) row = lvl2[row];
    float4 v = *(const float4*)(src + (size_t)row * 512 + threadIdx.x * 4);
    *(float4*)(out + (size_t)b * 512 + threadIdx.x * 4) = v;
}

// ---------------------------------------------------------------------------
// Transpose fp32 [R][C] -> bf16 [C][R]  (for the weight matrices; tiny)
// ---------------------------------------------------------------------------
__global__ __launch_bounds__(256) void transpose_to_bf16(
    const float* __restrict__ in, u16* __restrict__ out, int R, int C)
{
    __shared__ float t[32][33];
    const int r0 = blockIdx.x * 32, c0 = blockIdx.y * 32;
    const int tr = threadIdx.x >> 3;
    const int tc = (threadIdx.x & 7) * 4;
    float4 v = *(const float4*)(in + (size_t)(r0 + tr) * C + c0 + tc);
    t[tr][tc] = v.x; t[tr][tc + 1] = v.y; t[tr][tc + 2] = v.z; t[tr][tc + 3] = v.w;
    __syncthreads();
    ushort4 o;
    o.x = f2bf(t[tc + 0][tr]); o.y = f2bf(t[tc + 1][tr]);
    o.z = f2bf(t[tc + 2][tr]); o.w = f2bf(t[tc + 3][tr]);
    *(ushort4*)(out + (size_t)(c0 + tr) * R + r0 + tc) = o;
}

// ---------------------------------------------------------------------------
// MFMA GEMM:  C[M][N] = op( [A0 | A1] @ B )  with A fp32 row-major (converted
// to bf16 in staging), B given pre-transposed as BT[N][K] bf16 row-major.
// A0 covers k<K0 (stride K0), A1 covers k>=K0 (stride K-K0).
// Tiles: 128(M) x 64(N) x 32(K); 256 threads = 4 waves, wave-tile 64x32.
// mfma_f32_16x16x32_bf16:  A[m=lane&15][k=(lane>>4)*8+j],
//                          B[k=(lane>>4)*8+j][n=lane&15],
//                          C col=lane&15, row=(lane>>4)*4+reg   (m89-verified)
// ---------------------------------------------------------------------------
template<int RELU>
__global__ __launch_bounds__(256) void mfma_gemm(
    const float* __restrict__ A0, const float* __restrict__ A1, int K0,
    const u16* __restrict__ BT, float* __restrict__ Cout,
    int M, int N, int K)
{
    __shared__ u16 As[128][40];   // stride 80 B: 16B-aligned frags, 2-way banks (free)
    __shared__ u16 Bs[64][40];

    const int tid = threadIdx.x;
    const int m0 = blockIdx.x * 128;
    const int n0 = blockIdx.y * 64;
    const int wave = tid >> 6, lane = tid & 63;
    const int wm = (wave >> 1) * 64;
    const int wn = (wave & 1) * 32;
    const int fm = lane & 15, q = lane >> 4;

    f32x4 acc[4][2];
    #pragma unroll
    for (int i = 0; i < 4; ++i)
        #pragma unroll
        for (int j = 0; j < 2; ++j) acc[i][j] = (f32x4){0.f, 0.f, 0.f, 0.f};

    const int ar = tid >> 1;            // 0..127
    const int ac = (tid & 1) << 4;      // 0 / 16
    const int br = tid >> 2;            // 0..63
    const int bc = (tid & 3) << 3;      // 0/8/16/24
    const int strideA1 = K - K0;

    for (int k0 = 0; k0 < K; k0 += 32) {
        const float* ap;
        if (k0 < K0) ap = A0 + (size_t)(m0 + ar) * K0 + k0 + ac;
        else         ap = A1 + (size_t)(m0 + ar) * strideA1 + (k0 - K0) + ac;
        float4 v0 = *(const float4*)(ap + 0);
        float4 v1 = *(const float4*)(ap + 4);
        float4 v2 = *(const float4*)(ap + 8);
        float4 v3 = *(const float4*)(ap + 12);
        ushort8v u0, u1;
        u0[0] = f2bf(v0.x); u0[1] = f2bf(v0.y); u0[2] = f2bf(v0.z); u0[3] = f2bf(v0.w);
        u0[4] = f2bf(v1.x); u0[5] = f2bf(v1.y); u0[6] = f2bf(v1.z); u0[7] = f2bf(v1.w);
        u1[0] = f2bf(v2.x); u1[1] = f2bf(v2.y); u1[2] = f2bf(v2.z); u1[3] = f2bf(v2.w);
        u1[4] = f2bf(v3.x); u1[5] = f2bf(v3.y); u1[6] = f2bf(v3.z); u1[7] = f2bf(v3.w);
        *(ushort8v*)&As[ar][ac]     = u0;
        *(ushort8v*)&As[ar][ac + 8] = u1;

        const u16* bp = BT + (size_t)(n0 + br) * K + k0 + bc;
        *(uint4*)&Bs[br][bc] = *(const uint4*)bp;

        __syncthreads();

        short8 af[4], bf[2];
        #pragma unroll
        for (int mi = 0; mi < 4; ++mi)
            af[mi] = *(short8*)&As[wm + mi * 16 + fm][q * 8];
        #pragma unroll
        for (int ni = 0; ni < 2; ++ni)
            bf[ni] = *(short8*)&Bs[wn + ni * 16 + fm][q * 8];
        #pragma unroll
        for (int mi = 0; mi < 4; ++mi)
            #pragma unroll
            for (int ni = 0; ni < 2; ++ni)
                acc[mi][ni] = __builtin_amdgcn_mfma_f32_16x16x32_bf16(
                    af[mi], bf[ni], acc[mi][ni], 0, 0, 0);

        __syncthreads();
    }

    #pragma unroll
    for (int mi = 0; mi < 4; ++mi)
        #pragma unroll
        for (int ni = 0; ni < 2; ++ni)
            #pragma unroll
            for (int r = 0; r < 4; ++r) {
                int row = m0 + wm + mi * 16 + q * 4 + r;
                int col = n0 + wn + ni * 16 + fm;
                float v = acc[mi][ni][r];
                if (RELU) v = fmaxf(v, 0.f);
                Cout[(size_t)row * N + col] = v;
            }
}

// ---------------------------------------------------------------------------
// Classifier + softmax: out[m][c] = softmax(h2[m,:] @ wcls)[c].  fp32.
// ---------------------------------------------------------------------------
__global__ __launch_bounds__(128) void cls_softmax(
    const float* __restrict__ h2, const float* __restrict__ wcls,
    float* __restrict__ out)
{
    __shared__ float row[512];
    __shared__ float red[128];
    const int m = blockIdx.x, c = threadIdx.x;
    *(float4*)&row[c * 4] = *(const float4*)(h2 + (size_t)m * 512 + c * 4);
    __syncthreads();
    float acc = 0.f;
    #pragma unroll 8
    for (int k = 0; k < 512; ++k) acc += row[k] * wcls[k * 128 + c];
    red[c] = acc; __syncthreads();
    for (int s = 64; s > 0; s >>= 1) {
        if (c < s) red[c] = fmaxf(red[c], red[c + s]);
        __syncthreads();
    }
    float mx = red[0]; __syncthreads();
    float e = expf(acc - mx);
    red[c] = e; __syncthreads();
    for (int s = 64; s > 0; s >>= 1) {
        if (c < s) red[c] += red[c + s];
        __syncthreads();
    }
    out[(size_t)m * 128 + c] = e / red[0];
}

// ---------------------------------------------------------------------------
extern "C" void kernel_launch(void* const* d_in, const int* in_sizes, int n_in,
                              void* d_out, int out_size, void* d_ws, size_t ws_size,
                              hipStream_t stream)
{
    (void)in_sizes; (void)n_in; (void)out_size; (void)ws_size;
    const float* features = (const float*)d_in[0];
    const int*   src_nodes = (const int*)d_in[1];
    const int*   dst_idx1  = (const int*)d_in[2];
    const int*   src_idx1  = (const int*)d_in[3];
    const float* dif1      = (const float*)d_in[4];
    const int*   dst_idx2  = (const int*)d_in[5];
    const int*   src_idx2  = (const int*)d_in[6];
    const float* dif2      = (const float*)d_in[7];
    const float* w1        = (const float*)d_in[8];
    const float* w2        = (const float*)d_in[9];
    const float* wcls      = (const float*)d_in[10];
    float* out = (float*)d_out;

    char* ws = (char*)d_ws;
    // region 0 (0..32MB): xs1T during layer1; reused for layer-2 buffers after.
    u16*   xs1T   = (u16*)(ws + 0);                       // 512x32768 bf16 = 32 MB
    u16*   h1selT = (u16*)(ws + 0);                       // 512x3584 bf16 (alias, after gemm1)
    float* h1dst  = (float*)(ws + 8u  * 1024 * 1024);     // 512x512 f32
    float* agg2   = (float*)(ws + 12u * 1024 * 1024);     // 512x512 f32
    float* h2     = (float*)(ws + 16u * 1024 * 1024);     // 512x512 f32
    u16*   w1T    = (u16*)(ws + 33554432ull);             // 512x1024 bf16
    u16*   w2T    = (u16*)(ws + 33554432ull + 1048576);
    float* xd1    = (float*)(ws + 33554432ull + 2097152);             // 4096x512 f32 = 8 MB
    float* agg1   = (float*)(ws + 33554432ull + 2097152 + 8388608);   // 8 MB
    float* h1     = (float*)(ws + 33554432ull + 2097152 + 16777216);  // 8 MB

    // Layer-1 operand prep
    gather_transpose_bf16<<<32768 / 32, 256, 0, stream>>>(features, src_idx1, src_nodes, xs1T, 32768);
    gather_rows_f32<<<4096, 128, 0, stream>>>(features, dst_idx1, src_nodes, xd1);
    transpose_to_bf16<<<dim3(32, 16), 256, 0, stream>>>(w1, w1T, 1024, 512);
    transpose_to_bf16<<<dim3(32, 16), 256, 0, stream>>>(w2, w2T, 1024, 512);

    // agg1 = dif1 @ xs1          (M=4096, N=512, K=32768)  -- dominant GEMM
    mfma_gemm<0><<<dim3(32, 8), 256, 0, stream>>>(dif1, nullptr, 32768, xs1T, agg1, 4096, 512, 32768);
    // h1 = relu([agg1 | xd1] @ w1)   (M=4096, N=512, K=1024)
    mfma_gemm<1><<<dim3(32, 8), 256, 0, stream>>>(agg1, xd1, 512, w1T, h1, 4096, 512, 1024);

    // Layer-2 operand prep
    gather_transpose_bf16<<<3584 / 32, 256, 0, stream>>>(h1, src_idx2, nullptr, h1selT, 3584);
    gather_rows_f32<<<512, 128, 0, stream>>>(h1, dst_idx2, nullptr, h1dst);

    // agg2 = dif2 @ h1sel        (M=512, N=512, K=3584)
    mfma_gemm<0><<<dim3(4, 8), 256, 0, stream>>>(dif2, nullptr, 3584, h1selT, agg2, 512, 512, 3584);
    // h2 = relu([agg2 | h1dst] @ w2)
    mfma_gemm<1><<<dim3(4, 8), 256, 0, stream>>>(agg2, h1dst, 512, w2T, h2, 512, 512, 1024);

    // out = softmax(h2 @ wcls)
    cls_softmax<<<512, 128, 0, stream>>>(h2, wcls, out);
}

// Round 2
// 1203.045 us; speedup vs baseline: 1.7379x; 1.7379x over previous
//
#include <hip/hip_runtime.h>

typedef unsigned short u16;
typedef unsigned int u32;
typedef __attribute__((ext_vector_type(8))) short short8;
typedef __attribute__((ext_vector_type(4))) float f32x4;
typedef __attribute__((ext_vector_type(8))) u16 ushort8v;

__device__ __forceinline__ u16 f2bf(float f) {
    union { float f; u32 u; } v; v.f = f;
    return (u16)((v.u + 0x7FFFu + ((v.u >> 16) & 1u)) >> 16);
}
__device__ __forceinline__ u32 pack2bf(float a, float b) {
    union { float f; u32 u; } x, y; x.f = a; y.f = b;
    u32 ra = x.u + 0x7FFFu + ((x.u >> 16) & 1u);
    u32 rb = y.u + 0x7FFFu + ((y.u >> 16) & 1u);
    return (ra >> 16) | (rb & 0xFFFF0000u);
}

// ---------------------------------------------------------------------------
// Gather rows of a [*,512] fp32 matrix (1 or 2 level indirection), write the
// TRANSPOSE as bf16: outT[f][s]. 32 s per block, rows fully parallel.
// ---------------------------------------------------------------------------
__global__ __launch_bounds__(256) void gather_transpose_bf16(
    const float* __restrict__ src, const int* __restrict__ lvl1,
    const int* __restrict__ lvl2, u16* __restrict__ outT, int S)
{
    __shared__ u16 tile[32][514];
    const int s0 = blockIdx.x * 32;
    const int tid = threadIdx.x;
    const int r = tid >> 3;          // 0..31 : row within tile
    const int fb = (tid & 7) * 4;    // float4 base col

    int row = lvl1[s0 + r];
    if (lvl2) row = lvl2[row];
    const float* sp = src + (size_t)row * 512;
    #pragma unroll
    for (int j = 0; j < 16; ++j) {
        float4 v = *(const float4*)(sp + fb + j * 32);
        *(u32*)&tile[r][fb + j * 32]     = pack2bf(v.x, v.y);
        *(u32*)&tile[r][fb + j * 32 + 2] = pack2bf(v.z, v.w);
    }
    __syncthreads();

    #pragma unroll
    for (int i = 0; i < 8; ++i) {
        int f = i * 64 + (tid >> 2);
        int sb = (tid & 3) * 8;
        ushort8v o;
        #pragma unroll
        for (int j = 0; j < 8; ++j) o[j] = tile[sb + j][f];
        *(ushort8v*)(outT + (size_t)f * S + s0 + sb) = o;
    }
}

// ---------------------------------------------------------------------------
// Plain row gather, fp32 -> fp32, F=512.
// ---------------------------------------------------------------------------
__global__ __launch_bounds__(128) void gather_rows_f32(
    const float* __restrict__ src, const int* __restrict__ lvl1,
    const int* __restrict__ lvl2, float* __restrict__ out)
{
    int b = blockIdx.x;
    int row = lvl1[b];
    if (lvl2) row = lvl2[row];
    float4 v = *(const float4*)(src + (size_t)row * 512 + threadIdx.x * 4);
    *(float4*)(out + (size_t)b * 512 + threadIdx.x * 4) = v;
}

// ---------------------------------------------------------------------------
// Transpose fp32 [R][C] -> bf16 [C][R]  (weights; tiny)
// ---------------------------------------------------------------------------
__global__ __launch_bounds__(256) void transpose_to_bf16(
    const float* __restrict__ in, u16* __restrict__ out, int R, int C)
{
    __shared__ float t[32][33];
    const int r0 = blockIdx.x * 32, c0 = blockIdx.y * 32;
    const int tr = threadIdx.x >> 3;
    const int tc = (threadIdx.x & 7) * 4;
    float4 v = *(const float4*)(in + (size_t)(r0 + tr) * C + c0 + tc);
    t[tr][tc] = v.x; t[tr][tc + 1] = v.y; t[tr][tc + 2] = v.z; t[tr][tc + 3] = v.w;
    __syncthreads();
    ushort4 o;
    o.x = f2bf(t[tc + 0][tr]); o.y = f2bf(t[tc + 1][tr]);
    o.z = f2bf(t[tc + 2][tr]); o.w = f2bf(t[tc + 3][tr]);
    *(ushort4*)(out + (size_t)(c0 + tr) * R + r0 + tc) = o;
}

// ---------------------------------------------------------------------------
// Split-K MFMA GEMM: part[split] = op([A0|A1] @ B) over k-chunk.
// A fp32 row-major (converted to bf16 while staging), BT bf16 [N][K].
// BM=BN=128, BK=32; 256 thr = 4 waves (2x2), wave-tile 64x64.
// grid = (N/128, M/128, splits); n fastest so consecutive blocks share A.
// C/D layout (m89-verified): col=lane&15, row=(lane>>4)*4+reg.
// ---------------------------------------------------------------------------
__global__ __launch_bounds__(256, 3) void mfma_gemm_splitk(
    const float* __restrict__ A0, const float* __restrict__ A1, int K0,
    const u16* __restrict__ BT, float* __restrict__ part,
    int M, int N, int K)
{
    __shared__ u16 As[128][40];
    __shared__ u16 Bs[128][40];

    const int tid = threadIdx.x;
    const int n0 = blockIdx.x * 128;
    const int m0 = blockIdx.y * 128;
    const int kchunk = K / gridDim.z;
    const int kbeg = blockIdx.z * kchunk;
    const int kend = kbeg + kchunk;

    const int wave = tid >> 6, lane = tid & 63;
    const int wm = (wave >> 1) * 64;
    const int wn = (wave & 1) * 64;
    const int fm = lane & 15, q = lane >> 4;

    f32x4 acc[4][4];
    #pragma unroll
    for (int i = 0; i < 4; ++i)
        #pragma unroll
        for (int j = 0; j < 4; ++j) acc[i][j] = (f32x4){0.f, 0.f, 0.f, 0.f};

    const int ar = tid >> 1;          // 0..127
    const int ac = (tid & 1) << 4;    // 0 / 16
    const int sA1 = K - K0;

    for (int k0 = kbeg; k0 < kend; k0 += 32) {
        const float* ap = (k0 < K0)
            ? (A0 + (size_t)(m0 + ar) * K0 + k0 + ac)
            : (A1 + (size_t)(m0 + ar) * sA1 + (k0 - K0) + ac);
        float4 v0 = *(const float4*)(ap + 0);
        float4 v1 = *(const float4*)(ap + 4);
        float4 v2 = *(const float4*)(ap + 8);
        float4 v3 = *(const float4*)(ap + 12);
        uint4 w0, w1;
        w0.x = pack2bf(v0.x, v0.y); w0.y = pack2bf(v0.z, v0.w);
        w0.z = pack2bf(v1.x, v1.y); w0.w = pack2bf(v1.z, v1.w);
        w1.x = pack2bf(v2.x, v2.y); w1.y = pack2bf(v2.z, v2.w);
        w1.z = pack2bf(v3.x, v3.y); w1.w = pack2bf(v3.z, v3.w);

        const u16* bp = BT + (size_t)(n0 + ar) * K + k0 + ac;
        uint4 b0 = *(const uint4*)bp;
        uint4 b1 = *(const uint4*)(bp + 8);

        *(uint4*)&As[ar][ac]     = w0;
        *(uint4*)&As[ar][ac + 8] = w1;
        *(uint4*)&Bs[ar][ac]     = b0;
        *(uint4*)&Bs[ar][ac + 8] = b1;

        __syncthreads();

        short8 af[4], bf[4];
        #pragma unroll
        for (int mi = 0; mi < 4; ++mi)
            af[mi] = *(short8*)&As[wm + mi * 16 + fm][q * 8];
        #pragma unroll
        for (int ni = 0; ni < 4; ++ni)
            bf[ni] = *(short8*)&Bs[wn + ni * 16 + fm][q * 8];
        #pragma unroll
        for (int mi = 0; mi < 4; ++mi)
            #pragma unroll
            for (int ni = 0; ni < 4; ++ni)
                acc[mi][ni] = __builtin_amdgcn_mfma_f32_16x16x32_bf16(
                    af[mi], bf[ni], acc[mi][ni], 0, 0, 0);

        __syncthreads();
    }

    float* dst = part + (size_t)blockIdx.z * M * N;
    #pragma unroll
    for (int mi = 0; mi < 4; ++mi)
        #pragma unroll
        for (int ni = 0; ni < 4; ++ni)
            #pragma unroll
            for (int r = 0; r < 4; ++r) {
                int row = m0 + wm + mi * 16 + q * 4 + r;
                int col = n0 + wn + ni * 16 + fm;
                dst[(size_t)row * N + col] = acc[mi][ni][r];
            }
}

// ---------------------------------------------------------------------------
// out = op(sum over S partials), float4 vectorized.
// ---------------------------------------------------------------------------
template<int RELU>
__global__ __launch_bounds__(256) void reduce_partials(
    const float4* __restrict__ part, float4* __restrict__ out, int MN4, int S)
{
    int i = blockIdx.x * 256 + threadIdx.x;
    if (i >= MN4) return;
    float4 a = part[i];
    for (int s = 1; s < S; ++s) {
        float4 b = part[(size_t)s * MN4 + i];
        a.x += b.x; a.y += b.y; a.z += b.z; a.w += b.w;
    }
    if (RELU) {
        a.x = fmaxf(a.x, 0.f); a.y = fmaxf(a.y, 0.f);
        a.z = fmaxf(a.z, 0.f); a.w = fmaxf(a.w, 0.f);
    }
    out[i] = a;
}

// ---------------------------------------------------------------------------
// Classifier + softmax.
// ---------------------------------------------------------------------------
__global__ __launch_bounds__(128) void cls_softmax(
    const float* __restrict__ h2, const float* __restrict__ wcls,
    float* __restrict__ out)
{
    __shared__ float row[512];
    __shared__ float red[128];
    const int m = blockIdx.x, c = threadIdx.x;
    *(float4*)&row[c * 4] = *(const float4*)(h2 + (size_t)m * 512 + c * 4);
    __syncthreads();
    float acc = 0.f;
    #pragma unroll 8
    for (int k = 0; k < 512; ++k) acc += row[k] * wcls[k * 128 + c];
    red[c] = acc; __syncthreads();
    for (int s = 64; s > 0; s >>= 1) {
        if (c < s) red[c] = fmaxf(red[c], red[c + s]);
        __syncthreads();
    }
    float mx = red[0]; __syncthreads();
    float e = expf(acc - mx);
    red[c] = e; __syncthreads();
    for (int s = 64; s > 0; s >>= 1) {
        if (c < s) red[c] += red[c + s];
        __syncthreads();
    }
    out[(size_t)m * 128 + c] = e / red[0];
}

// ---------------------------------------------------------------------------
extern "C" void kernel_launch(void* const* d_in, const int* in_sizes, int n_in,
                              void* d_out, int out_size, void* d_ws, size_t ws_size,
                              hipStream_t stream)
{
    (void)in_sizes; (void)n_in; (void)out_size;
    const float* features  = (const float*)d_in[0];
    const int*   src_nodes = (const int*)d_in[1];
    const int*   dst_idx1  = (const int*)d_in[2];
    const int*   src_idx1  = (const int*)d_in[3];
    const float* dif1      = (const float*)d_in[4];
    const int*   dst_idx2  = (const int*)d_in[5];
    const int*   src_idx2  = (const int*)d_in[6];
    const float* dif2      = (const float*)d_in[7];
    const float* w1        = (const float*)d_in[8];
    const float* w2        = (const float*)d_in[9];
    const float* wcls      = (const float*)d_in[10];
    float* out = (float*)d_out;

    const size_t MB = 1024ull * 1024ull;
    // split-K factor for gemm1 limited by scratch: partials = splits1 * 8 MB
    int splits1 = (ws_size >= 102 * MB) ? 8 : ((ws_size >= 70 * MB) ? 4 : 2);

    char* ws = (char*)d_ws;
    u16*   xs1T   = (u16*)ws;                 // 32 MB  [0,32)   (dead after gemm1)
    float* agg1   = (float*)ws;               // 8 MB   [0,8)    (after gemm1)
    float* xd1    = (float*)(ws + 8 * MB);    // 8 MB   [8,16)   (after gemm1)
    float* h1     = (float*)(ws + 16 * MB);   // 8 MB   [16,24)
    u16*   h1selT = (u16*)(ws + 24 * MB);     // 3.5 MB [24,27.5) (after gemm2)
    float* h1dst  = (float*)(ws + 28 * MB);   // 1 MB   [28,29)
    float* part   = (float*)(ws + 32 * MB);   // splits1*8 MB
    size_t po = 32 * MB + (size_t)splits1 * 8 * MB;
    u16*   w1T  = (u16*)(ws + po); po += MB;
    u16*   w2T  = (u16*)(ws + po); po += MB;
    float* agg2 = (float*)(ws + po); po += MB;
    float* h2   = (float*)(ws + po); po += MB;

    // weight transposes (independent)
    transpose_to_bf16<<<dim3(32, 16), 256, 0, stream>>>(w1, w1T, 1024, 512);
    transpose_to_bf16<<<dim3(32, 16), 256, 0, stream>>>(w2, w2T, 1024, 512);

    // layer-1 src gather+transpose
    gather_transpose_bf16<<<32768 / 32, 256, 0, stream>>>(features, src_idx1, src_nodes, xs1T, 32768);

    // gemm1: agg1 = dif1 @ xs1   (M=4096, N=512, K=32768)
    mfma_gemm_splitk<<<dim3(4, 32, splits1), 256, 0, stream>>>(
        dif1, nullptr, 32768, xs1T, part, 4096, 512, 32768);
    reduce_partials<0><<<2048, 256, 0, stream>>>((const float4*)part, (float4*)agg1, 524288, splits1);

    // dst gather (into region freed by xs1T)
    gather_rows_f32<<<4096, 128, 0, stream>>>(features, dst_idx1, src_nodes, xd1);

    // gemm2: h1 = relu([agg1 | xd1] @ w1)   (M=4096, N=512, K=1024)
    mfma_gemm_splitk<<<dim3(4, 32, 2), 256, 0, stream>>>(
        agg1, xd1, 512, w1T, part, 4096, 512, 1024);
    reduce_partials<1><<<2048, 256, 0, stream>>>((const float4*)part, (float4*)h1, 524288, 2);

    // layer-2 gathers
    gather_transpose_bf16<<<3584 / 32, 256, 0, stream>>>(h1, src_idx2, nullptr, h1selT, 3584);
    gather_rows_f32<<<512, 128, 0, stream>>>(h1, dst_idx2, nullptr, h1dst);

    // gemm3: agg2 = dif2 @ h1sel   (M=512, N=512, K=3584)
    mfma_gemm_splitk<<<dim3(4, 4, 8), 256, 0, stream>>>(
        dif2, nullptr, 3584, h1selT, part, 512, 512, 3584);
    reduce_partials<0><<<256, 256, 0, stream>>>((const float4*)part, (float4*)agg2, 65536, 8);

    // gemm4: h2 = relu([agg2 | h1dst] @ w2)   (M=512, N=512, K=1024)
    mfma_gemm_splitk<<<dim3(4, 4, 4), 256, 0, stream>>>(
        agg2, h1dst, 512, w2T, part, 512, 512, 1024);
    reduce_partials<1><<<256, 256, 0, stream>>>((const float4*)part, (float4*)h2, 65536, 4);

    // classifier + softmax
    cls_softmax<<<512, 128, 0, stream>>>(h2, wcls, out);
}